// Round 12
// baseline (335.254 us; speedup 1.0000x reference)
//
#include <hip/hip_runtime.h>
#include <hip/hip_fp16.h>

#define B_ 4096
#define T_ 64
#define NROWS (B_*T_)      // 262144
#define BLOB_B 2099200     // byte offset of weight blob in ws
#define JD_REL 163840      // jd_w1 K=256 image offset WITHIN blob (64 KB)
#define PIMG_B (BLOB_B + 229376)      // param image (4 KB f16), absolute in ws

typedef _Float16 f16x8 __attribute__((ext_vector_type(8)));
typedef float    f32x4 __attribute__((ext_vector_type(4)));

__device__ __forceinline__ float gelu_f(float x){
    return 0.5f * x * (1.0f + erff(x * 0.70710678118654752f));
}

// ---------- async global->LDS, 16B per lane, linear dest ----------
__device__ __forceinline__ void gll16(const void* g, void* l){
    __builtin_amdgcn_global_load_lds(
        (const __attribute__((address_space(1))) void*)g,
        (__attribute__((address_space(3))) void*)l, 16, 0, 0);
}

// stage 32KB image with 512 threads: 4 issues per lane (8KB per round)
__device__ __forceinline__ void stage32(const char* gsrc, char* dst, int wave, int lane){
#pragma unroll
    for (int r = 0; r < 4; r++){
        const int off = r * 8192 + wave * 1024;
        gll16(gsrc + off + lane * 16, dst + off);
    }
}

// stage 4KB param image: waves 0..3 only
__device__ __forceinline__ void stage_p(const char* gsrc, char* dst, int wave, int lane){
    if (wave < 4) gll16(gsrc + wave * 1024 + lane * 16, dst + wave * 1024);
}

// ---------- input rows -> f16 A-fragments (K=128 -> 4 frags)
__device__ __forceinline__ void load_in(f16x8* a, const float* __restrict__ p, int g){
#pragma unroll
    for (int ks = 0; ks < 4; ks++){
        const float* q = p + ks * 32 + g * 8;
        float4 v0 = *(const float4*)q, v1 = *(const float4*)(q + 4);
        f16x8 t;
        t[0]=(_Float16)v0.x; t[1]=(_Float16)v0.y; t[2]=(_Float16)v0.z; t[3]=(_Float16)v0.w;
        t[4]=(_Float16)v1.x; t[5]=(_Float16)v1.y; t[6]=(_Float16)v1.z; t[7]=(_Float16)v1.w;
        a[ks] = t;
    }
}

// ---------- A-fragments from wave-private ab tile [16][128] f16
__device__ __forceinline__ void load_a(f16x8* a, const char* ab, int c, int g){
    const int rswz = (c & 7) << 4;
    const char* rp = ab + c * 256;
#pragma unroll
    for (int ks = 0; ks < 4; ks++)
        a[ks] = *(const f16x8*)(rp + ((ks * 64 + g * 16) ^ rswz));
}

// ---------- 8-tile MFMA, K=128, row stride 256B
__device__ __forceinline__ void mfma_tile(f32x4* acc, const f16x8* a,
                                          const char* wb, int c, int g){
#pragma unroll
    for (int n = 0; n < 8; n++){
        const int r = n * 16 + c;
        const char* rp = wb + r * 256;
        const int swz = (r & 7) << 4;
#pragma unroll
        for (int ks = 0; ks < 4; ks++){
            f16x8 b = *(const f16x8*)(rp + ((ks * 64 + g * 16) ^ swz));
            acc[n] = __builtin_amdgcn_mfma_f32_16x16x32_f16(a[ks], b, acc[n], 0, 0, 0);
        }
    }
}

// ---------- 8-tile MFMA half of K=256 (row stride 512B), koff = 0 or 256 bytes
__device__ __forceinline__ void mfma_tile8h(f32x4* acc, const f16x8* a,
                                            const char* wb, int c, int g, int koff){
#pragma unroll
    for (int n = 0; n < 8; n++){
        const int r = n * 16 + c;
        const char* rp = wb + r * 512 + koff;   // swz<128 so XOR stays within half
        const int swz = (r & 7) << 4;
#pragma unroll
        for (int ks = 0; ks < 4; ks++){
            f16x8 b = *(const f16x8*)(rp + ((ks * 64 + g * 16) ^ swz));
            acc[n] = __builtin_amdgcn_mfma_f32_16x16x32_f16(a[ks], b, acc[n], 0, 0, 0);
        }
    }
}

// ---------- LN'd A-fragments in registers
__device__ __forceinline__ void build_y(f16x8* y, const f16x8* x, float mu, float rs,
                                        const char* sp, int goff, int boff, int g){
#pragma unroll
    for (int ks = 0; ks < 4; ks++){
        f16x8 gam = *(const f16x8*)(sp + goff * 2 + ks * 64 + g * 16);
        f16x8 bet = *(const f16x8*)(sp + boff * 2 + ks * 64 + g * 16);
        f16x8 t;
#pragma unroll
        for (int j = 0; j < 8; j++){
            float v = ((float)x[ks][j] - mu) * rs * (float)gam[j] + (float)bet[j];
            t[j] = (_Float16)v;
        }
        y[ks] = t;
    }
}

// ---------- per-row stats over lane's 32 elems + 4-lane-group reduce
__device__ __forceinline__ void row_stats(const f16x8* x, float& s0, float& s1){
    s0 = 0.f; s1 = 0.f;
#pragma unroll
    for (int ks = 0; ks < 4; ks++)
#pragma unroll
        for (int j = 0; j < 8; j++){ float v = (float)x[ks][j]; s0 += v; s1 += v*v; }
    s0 += __shfl_xor(s0, 16); s0 += __shfl_xor(s0, 32);
    s1 += __shfl_xor(s1, 16); s1 += __shfl_xor(s1, 32);
}

// ---------- logits + CE from C-layout acc (shfl-dot over 16 c-lanes)
__device__ __forceinline__ void logits_ce(const f32x4* acc, const char* sp,
                                          int b1off, int w2off, const float* __restrict__ b2,
                                          int c, int g, int lab, float* ce){
    const _Float16* sbf = (const _Float16*)sp;
    float l0[4] = {0,0,0,0}, l1[4] = {0,0,0,0};
#pragma unroll
    for (int n = 0; n < 8; n++){
        const int r = n * 16 + c;
        float b1v = (float)sbf[b1off + r];
        float wx  = (float)sbf[w2off + 2 * r];
        float wy  = (float)sbf[w2off + 2 * r + 1];
#pragma unroll
        for (int rr = 0; rr < 4; rr++){
            float hv = gelu_f(acc[n][rr] + b1v);
            l0[rr] += hv * wx; l1[rr] += hv * wy;
        }
    }
    const float b2x = b2[0], b2y = b2[1];   // load at use: no long-lived regs
#pragma unroll
    for (int rr = 0; rr < 4; rr++){
#pragma unroll
        for (int m = 1; m < 16; m <<= 1){ l0[rr] += __shfl_xor(l0[rr], m); l1[rr] += __shfl_xor(l1[rr], m); }
        float v0 = l0[rr] + b2x, v1 = l1[rr] + b2y;
        float mx = fmaxf(v0, v1);
        float lse = mx + logf(expf(v0 - mx) + expf(v1 - mx));
        ce[rr] = lse - (lab ? v1 : v0);
    }
}

// ---------- MFMA phase with bias(+gelu) epilogue into ab tile
template<bool GELU>
__device__ __forceinline__ void phase_store(const f16x8* a, const char* wb, char* ab,
                                            const char* sp, int boff, int c, int g){
    const _Float16* sbf = (const _Float16*)sp;
    f32x4 acc[8];
#pragma unroll
    for (int n = 0; n < 8; n++) acc[n] = (f32x4){0.f,0.f,0.f,0.f};
    mfma_tile(acc, a, wb, c, g);
#pragma unroll
    for (int n = 0; n < 8; n++){
        const int col = n * 16 + c;
        float bi = (float)sbf[boff + col];
#pragma unroll
        for (int rr = 0; rr < 4; rr++){
            float v = acc[n][rr] + bi;
            if (GELU) v = gelu_f(v);
            int row = g * 4 + rr;
            *(_Float16*)(ab + row * 256 + ((col << 1) ^ ((row & 7) << 4))) = (_Float16)v;
        }
    }
}

// ======================= prep + stats (merged) =============================
__global__ void k_prep(const float* __restrict__ ce_w1, const float* __restrict__ ce_w2,
                       const float* __restrict__ se_w1, const float* __restrict__ se_w2,
                       const float* __restrict__ cd_w1, const float* __restrict__ jd_w1,
                       const float* __restrict__ ce_b1, const float* __restrict__ ce_b2,
                       const float* __restrict__ se_b1, const float* __restrict__ se_b2,
                       const float* __restrict__ cd_g,  const float* __restrict__ cd_bt,
                       const float* __restrict__ cd_b1, const float* __restrict__ jd_g,
                       const float* __restrict__ jd_bt, const float* __restrict__ jd_b1,
                       const float* __restrict__ cd_w2, const float* __restrict__ jd_w2,
                       const int* __restrict__ mask, const int* __restrict__ labels,
                       float* __restrict__ ws){
    char* blob = (char*)ws + BLOB_B;
    const int bid = blockIdx.x, tid = threadIdx.x;
    if (bid < 320){
        int e = bid * 256 + tid;
        int m = e >> 14, idx = e & 16383;
        int k = idx >> 7, cc = idx & 127;
        const float* src;
        switch (m){
            case 0: src = ce_w1; break;
            case 1: src = ce_w2; break;
            case 2: src = se_w1; break;
            case 3: src = se_w2; break;
            default: src = cd_w1; break;
        }
        float v = src[k * 128 + cc];
        int byte = m * 32768 + cc * 256 + ((k << 1) ^ ((cc & 7) << 4));
        *(_Float16*)(blob + byte) = (_Float16)v;
    } else if (bid < 448){
        int e = (bid - 320) * 256 + tid;
        int k = e >> 7, cc = e & 127;
        float v = jd_w1[k * 128 + cc];
        int byte = JD_REL + cc * 512 + ((k << 1) ^ ((cc & 7) << 4));
        *(_Float16*)(blob + byte) = (_Float16)v;
    } else if (bid < 512){
        int t = bid - 448;
        float c0 = 0.f, c1 = 0.f;
        for (int b = tid; b < B_; b += 256){
            if (mask[b * T_ + t]){
                if (labels[b] == 1) c1 += 1.f; else c0 += 1.f;
            }
        }
        for (int m = 1; m < 64; m <<= 1){ c0 += __shfl_xor(c0, m); c1 += __shfl_xor(c1, m); }
        __shared__ float sh[8];
        int w = tid >> 6, l = tid & 63;
        if (l == 0){ sh[w] = c0; sh[4 + w] = c1; }
        __syncthreads();
        if (tid == 0){
            float a0 = sh[0] + sh[1] + sh[2] + sh[3];
            float a1 = sh[4] + sh[5] + sh[6] + sh[7];
            float tot = a0 + a1;
            float d = fmaxf(tot, 1.f);
            float p0 = a0 / d, p1 = a1 / d;
            float ent = -(p0 * logf(p0 + 1e-8f) + p1 * logf(p1 + 1e-8f));
            ws[t] = ent;
            ws[64 + t] = (tot >= 2.f) ? 1.f : 0.f;
            ws[128 + t] = tot;
        }
    } else {
        _Float16* p = (_Float16*)((char*)ws + PIMG_B);
        if (tid < 128){
            p[tid]       = (_Float16)ce_b1[tid]; p[128 + tid] = (_Float16)ce_b2[tid];
            p[256 + tid] = (_Float16)se_b1[tid]; p[384 + tid] = (_Float16)se_b2[tid];
            p[512 + tid] = (_Float16)cd_g[tid];  p[640 + tid] = (_Float16)cd_bt[tid];
            p[768 + tid] = (_Float16)cd_b1[tid]; p[896 + tid] = (_Float16)jd_b1[tid];
        } else {
            int i = tid - 128;
            p[1024 + i] = (_Float16)jd_g[i];        p[1152 + i] = (_Float16)jd_g[128 + i];
            p[1280 + i] = (_Float16)jd_bt[i];       p[1408 + i] = (_Float16)jd_bt[128 + i];
            p[1536 + 2*i] = (_Float16)cd_w2[2*i];   p[1537 + 2*i] = (_Float16)cd_w2[2*i+1];
            p[1792 + 2*i] = (_Float16)jd_w2[2*i];   p[1793 + 2*i] = (_Float16)jd_w2[2*i+1];
        }
    }
}

// ======================= main fused kernel =================================
// 512 threads (8 waves x 16 rows = 128 rows/block), grid 2048.
// LDS 69632: [0,32K)=wbuf | [32K,64K)=8 wave ab tiles | [64K,68K)=params.
// launch_bounds(512,4): total reg budget 128/wave (arch<=96 + 32 AGPR)
// -> 2 blocks/CU (16 waves/CU). Demand ~108 arch -> expect mild spill at most.
__global__ __launch_bounds__(512, 4) void k_main(
    const float* __restrict__ xc, const float* __restrict__ xs,
    const int* __restrict__ labels, const int* __restrict__ mask,
    const float* __restrict__ cd_b2, const float* __restrict__ jd_b2,
    float* __restrict__ ws, float* __restrict__ out)
{
    __shared__ __align__(16) char lds[69632];

    const int tid = threadIdx.x;
    const int wave = tid >> 6, lane = tid & 63;
    const int c = lane & 15, g = lane >> 4;
    const int wrow0 = blockIdx.x * 128 + wave * 16;
    char* const ab = lds + 32768 + wave * 4096;
    const char* sp = lds + 65536;
    const char* blob = (const char*)ws + BLOB_B;
    const int lab = labels[wrow0 >> 6];

    f16x8 fr[4], cr[4], sr[4];
    float ceC[4], ceJ[4];
    float s0c, s1c, mcv, rcv, jmv, jrv;

    // ---- P0: stage params + ce_w1; prefetch xc ----------------------------
    stage_p((const char*)ws + PIMG_B, lds + 65536, wave, lane);
    stage32(blob + 0 * 32768, lds, wave, lane);
    load_in(fr, xc + (wrow0 + c) * 128, g);
    __syncthreads();                                            // B1: ce_w1 ready

    // ---- P1: enc1 causal ---------------------------------------------------
    phase_store<true>(fr, lds, ab, sp, 0, c, g);
    __syncthreads();                                            // B2: ce_w1 retired
    stage32(blob + 1 * 32768, lds, wave, lane);                 // ce_w2
    load_a(fr, ab, c, g);                                       // filler
    __syncthreads();                                            // B3: ce_w2 ready

    // ---- P2: enc2 causal -> c_rep tile ------------------------------------
    phase_store<false>(fr, lds, ab, sp, 128, c, g);
    __syncthreads();                                            // B4: ce_w2 retired
    stage32(blob + 2 * 32768, lds, wave, lane);                 // se_w1
    load_in(fr, xs + (wrow0 + c) * 128, g);                     // xs load (overlapped)
    load_a(cr, ab, c, g);  row_stats(cr, s0c, s1c);             // fillers
    __syncthreads();                                            // B5: se_w1 ready

    // ---- P3: enc1 spurious -------------------------------------------------
    phase_store<true>(fr, lds, ab, sp, 256, c, g);
    __syncthreads();                                            // B6: se_w1 retired
    stage32(blob + 3 * 32768, lds, wave, lane);                 // se_w2
    load_a(fr, ab, c, g);                                       // filler
    __syncthreads();                                            // B7: se_w2 ready

    // ---- P4: enc2 spurious -> s_rep tile; all stats ------------------------
    phase_store<false>(fr, lds, ab, sp, 384, c, g);
    __syncthreads();                                            // B8: se_w2 retired
    stage32(blob + 4 * 32768, lds, wave, lane);                 // cd_w1
    {
        float s0s, s1s;
        load_a(sr, ab, c, g); row_stats(sr, s0s, s1s);
        mcv = s0c * (1.f/128.f);
        rcv = rsqrtf(s1c * (1.f/128.f) - mcv * mcv + 1e-5f);
        jmv = (s0c + s0s) * (1.f/256.f);
        jrv = rsqrtf((s1c + s1s) * (1.f/256.f) - jmv * jmv + 1e-5f);
    }
    __syncthreads();                                            // B9: cd_w1 ready; ab reads done
    stage32(blob + JD_REL + 32768, lds + 32768, wave, lane);    // jd cols 64..127 -> ab region

    // ---- P5: causal decoder (in-reg) + ceC ---------------------------------
    {
        f32x4 acc[8];
        build_y(fr, cr, mcv, rcv, sp, 512, 640, g);
#pragma unroll
        for (int n = 0; n < 8; n++) acc[n] = (f32x4){0.f,0.f,0.f,0.f};
        mfma_tile(acc, fr, lds, c, g);
        logits_ce(acc, sp, 768, 1536, cd_b2, c, g, lab, ceC);
    }
    __syncthreads();                                            // B10: cd_w1 retired; jd-upper landed
    stage32(blob + JD_REL, lds, wave, lane);                    // jd cols 0..63 -> wbuf
    build_y(fr, cr, jmv, jrv, sp, 1024, 1280, g);               // yjc frags (cr dies) under gll
    __syncthreads();                                            // B11: full jd image ready

    // ---- P6: joint decoder (K=256, two halves reusing fr) + epilogue -------
    {
        f32x4 acc[8];
#pragma unroll
        for (int n = 0; n < 8; n++) acc[n] = (f32x4){0.f,0.f,0.f,0.f};
        mfma_tile8h(acc, fr, lds, c, g, 0);                     // yjc @ jd k 0..127
        build_y(fr, sr, jmv, jrv, sp, 1152, 1408, g);           // yjs frags (sr dies)
        mfma_tile8h(acc, fr, lds, c, g, 256);                   // yjs @ jd k 128..255
        logits_ce(acc, sp, 896, 1792, jd_b2, c, g, lab, ceJ);
    }
    if (c == 0){
        const int rowbase = wrow0 + g * 4;
        const int4  m4 = *(const int4*)(mask + rowbase);
        const float4 e4 = *(const float4*)(ws + (rowbase & 63));
        const float4 s4 = *(const float4*)(ws + 64 + (rowbase & 63));
        const int   mm[4] = {m4.x, m4.y, m4.z, m4.w};
        const float ee[4] = {e4.x, e4.y, e4.z, e4.w};
        const float sv[4] = {s4.x, s4.y, s4.z, s4.w};
        float rw[4], mcw[4], mjw[4];
#pragma unroll
        for (int rr = 0; rr < 4; rr++){
            float mf = mm[rr] ? 1.f : 0.f;
            float cec = ceC[rr], cej = ceJ[rr];
            rw[rr]  = mf * sv[rr] * (ee[rr] - cec - 0.5f * fmaxf(cec - cej, 0.f));
            mcw[rr] = mf * cec;  mjw[rr] = mf * cej;
        }
        *(float4*)(out + rowbase)              = (float4){rw[0], rw[1], rw[2], rw[3]};
        *(float4*)(ws + 512 + rowbase)         = (float4){mcw[0], mcw[1], mcw[2], mcw[3]};
        *(float4*)(ws + 512 + NROWS + rowbase) = (float4){mjw[0], mjw[1], mjw[2], mjw[3]};
    }
}

// ======================= aux reductions ====================================
__global__ void k_aux1(float* __restrict__ ws){
    int t = blockIdx.x, tid = threadIdx.x;
    const float* mc = ws + 512;
    const float* mj = ws + 512 + NROWS;
    float sc = 0.f, sj = 0.f;
    for (int b = tid; b < B_; b += 256){ sc += mc[b * T_ + t]; sj += mj[b * T_ + t]; }
    for (int m = 1; m < 64; m <<= 1){ sc += __shfl_xor(sc, m); sj += __shfl_xor(sj, m); }
    __shared__ float sh[8];
    int w = tid >> 6, l = tid & 63;
    if (l == 0){ sh[w] = sc; sh[4 + w] = sj; }
    __syncthreads();
    if (tid == 0){
        float a0 = sh[0] + sh[1] + sh[2] + sh[3];
        float a1 = sh[4] + sh[5] + sh[6] + sh[7];
        ws[192 + t] = ws[64 + t] * 0.5f * (a0 + a1) / fmaxf(ws[128 + t], 1.f);
    }
}

__global__ void k_aux2(const float* __restrict__ ws, float* __restrict__ out){
    int l = threadIdx.x;
    float cv = ws[192 + l], sv = ws[64 + l];
    for (int m = 1; m < 64; m <<= 1){ cv += __shfl_xor(cv, m); sv += __shfl_xor(sv, m); }
    if (l == 0) out[NROWS] = (sv > 0.f) ? cv / fmaxf(sv, 1.f) : 0.f;
}

extern "C" void kernel_launch(void* const* d_in, const int* in_sizes, int n_in,
                              void* d_out, int out_size, void* d_ws, size_t ws_size,
                              hipStream_t stream) {
    const float* xc     = (const float*)d_in[0];
    const float* xs     = (const float*)d_in[1];
    const int*   labels = (const int*)d_in[2];
    const int*   mask   = (const int*)d_in[3];
    const float* ce_w1  = (const float*)d_in[4];
    const float* ce_b1  = (const float*)d_in[5];
    const float* ce_w2  = (const float*)d_in[6];
    const float* ce_b2  = (const float*)d_in[7];
    const float* se_w1  = (const float*)d_in[8];
    const float* se_b1  = (const float*)d_in[9];
    const float* se_w2  = (const float*)d_in[10];
    const float* se_b2  = (const float*)d_in[11];
    const float* cd_g   = (const float*)d_in[12];
    const float* cd_b   = (const float*)d_in[13];
    const float* cd_w1  = (const float*)d_in[14];
    const float* cd_b1  = (const float*)d_in[15];
    const float* cd_w2  = (const float*)d_in[16];
    const float* cd_b2  = (const float*)d_in[17];
    const float* jd_g   = (const float*)d_in[18];
    const float* jd_b   = (const float*)d_in[19];
    const float* jd_w1  = (const float*)d_in[20];
    const float* jd_b1  = (const float*)d_in[21];
    const float* jd_w2  = (const float*)d_in[22];
    const float* jd_b2  = (const float*)d_in[23];
    float* ws  = (float*)d_ws;
    float* out = (float*)d_out;

    k_prep<<<513, 256, 0, stream>>>(ce_w1, ce_w2, se_w1, se_w2, cd_w1, jd_w1,
                                    ce_b1, ce_b2, se_b1, se_b2, cd_g, cd_b,
                                    cd_b1, jd_g, jd_b, jd_b1, cd_w2, jd_w2,
                                    mask, labels, ws);
    k_main<<<2048, 512, 0, stream>>>(xc, xs, labels, mask, cd_b2, jd_b2, ws, out);
    k_aux1<<<64, 256, 0, stream>>>(ws);
    k_aux2<<<1, 64, 0, stream>>>(ws, out);
}

// Round 13
// 266.732 us; speedup vs baseline: 1.2569x; 1.2569x over previous
//
#include <hip/hip_runtime.h>
#include <hip/hip_fp16.h>

#define B_ 4096
#define T_ 64
#define NROWS (B_*T_)      // 262144
#define BLOB_B 2099200     // byte offset of weight blob in ws (after stats+mc+mj)
#define PIMG_B (BLOB_B + 7*32768)   // param image (4 KB f16)

typedef _Float16 f16x8 __attribute__((ext_vector_type(8)));
typedef float    f32x4 __attribute__((ext_vector_type(4)));

// tanh-form GELU: max |diff| vs exact-erf gelu ~3e-4, ~half the VALU cost of erff
__device__ __forceinline__ float gelu_f(float x){
    float u = 0.7978845608028654f * (x + 0.044715f * x * x * x);
    float t = 1.f - 2.f / (__expf(2.f * u) + 1.f);   // tanh(u)
    return 0.5f * x * (1.f + t);
}

// ---------- async global->LDS, 16B per lane, linear dest ----------
__device__ __forceinline__ void gll16(const void* g, void* l){
    __builtin_amdgcn_global_load_lds(
        (const __attribute__((address_space(1))) void*)g,
        (__attribute__((address_space(3))) void*)l, 16, 0, 0);
}

// stage one 32KB pre-swizzled weight image into wbuf (4 waves x 8 x 1KB)
__device__ __forceinline__ void stage_w(const char* gsrc, char* wbuf, int wave, int lane){
    const char* g = gsrc + wave * 8192 + lane * 16;
    char* l = wbuf + wave * 8192;
#pragma unroll
    for (int r = 0; r < 8; r++) gll16(g + r * 1024, l + r * 1024);
}

// stage 4KB param image (1 issue per wave)
__device__ __forceinline__ void stage_p(const char* gsrc, char* sp, int wave, int lane){
    gll16(gsrc + wave * 1024 + lane * 16, sp + wave * 1024);
}

// ---------- input rows -> f16 A-fragments (K=128 -> 4 frags)
__device__ __forceinline__ void load_in(f16x8* a, const float* __restrict__ p, int g){
#pragma unroll
    for (int ks = 0; ks < 4; ks++){
        const float* q = p + ks * 32 + g * 8;
        float4 v0 = *(const float4*)q, v1 = *(const float4*)(q + 4);
        f16x8 t;
        t[0]=(_Float16)v0.x; t[1]=(_Float16)v0.y; t[2]=(_Float16)v0.z; t[3]=(_Float16)v0.w;
        t[4]=(_Float16)v1.x; t[5]=(_Float16)v1.y; t[6]=(_Float16)v1.z; t[7]=(_Float16)v1.w;
        a[ks] = t;
    }
}

// ---------- A-fragments from wave-private abuf tile [16][128] f16
__device__ __forceinline__ void load_a(f16x8* a, const char* ab, int c, int g){
    const int rswz = (c & 7) << 4;
    const char* rp = ab + c * 256;
#pragma unroll
    for (int ks = 0; ks < 4; ks++)
        a[ks] = *(const f16x8*)(rp + ((ks * 64 + g * 16) ^ rswz));
}

// ---------- full 8-tile MFMA vs staged weights (K=128, row stride 256B)
__device__ __forceinline__ void mfma_tile(f32x4* acc, const f16x8* a,
                                          const unsigned short* wb, int c, int g){
#pragma unroll
    for (int n = 0; n < 8; n++){
        const int r = n * 16 + c;
        const char* rp = (const char*)wb + r * 256;
        const int swz = (r & 7) << 4;
#pragma unroll
        for (int ks = 0; ks < 4; ks++){
            f16x8 b = *(const f16x8*)(rp + ((ks * 64 + g * 16) ^ swz));
            acc[n] = __builtin_amdgcn_mfma_f32_16x16x32_f16(a[ks], b, acc[n], 0, 0, 0);
        }
    }
}

// ---------- LN'd A-fragments in registers
__device__ __forceinline__ void build_y(f16x8* y, const f16x8* x, float mu, float rs,
                                        const unsigned short* sbh, int goff, int boff, int g){
#pragma unroll
    for (int ks = 0; ks < 4; ks++){
        f16x8 gam = *(const f16x8*)((const char*)sbh + goff * 2 + ks * 64 + g * 16);
        f16x8 bet = *(const f16x8*)((const char*)sbh + boff * 2 + ks * 64 + g * 16);
        f16x8 t;
#pragma unroll
        for (int j = 0; j < 8; j++){
            float v = ((float)x[ks][j] - mu) * rs * (float)gam[j] + (float)bet[j];
            t[j] = (_Float16)v;
        }
        y[ks] = t;
    }
}

// ---------- logits + CE from C-layout acc (shfl-dot over 16 c-lanes)
__device__ __forceinline__ void logits_ce(const f32x4* acc, const unsigned short* sbh,
                                          int b1off, int w2off, const float* __restrict__ b2,
                                          int c, int g, int lab, float* ce){
    const _Float16* sbf = (const _Float16*)sbh;
    float l0[4] = {0,0,0,0}, l1[4] = {0,0,0,0};
#pragma unroll
    for (int n = 0; n < 8; n++){
        const int r = n * 16 + c;
        float b1v = (float)sbf[b1off + r];
        float wx  = (float)sbf[w2off + 2 * r];
        float wy  = (float)sbf[w2off + 2 * r + 1];
#pragma unroll
        for (int rr = 0; rr < 4; rr++){
            float hv = gelu_f(acc[n][rr] + b1v);
            l0[rr] += hv * wx; l1[rr] += hv * wy;
        }
    }
    const float b2x = b2[0], b2y = b2[1];   // load at use: no long-lived regs
#pragma unroll
    for (int rr = 0; rr < 4; rr++){
#pragma unroll
        for (int m = 1; m < 16; m <<= 1){ l0[rr] += __shfl_xor(l0[rr], m); l1[rr] += __shfl_xor(l1[rr], m); }
        float v0 = l0[rr] + b2x, v1 = l1[rr] + b2y;
        float mx = fmaxf(v0, v1);
        float lse = mx + logf(expf(v0 - mx) + expf(v1 - mx));
        ce[rr] = lse - (lab ? v1 : v0);
    }
}

// ======================= prep: weights -> f16 pre-swizzled LDS images ======
__global__ void k_prep(const float* __restrict__ ce_w1, const float* __restrict__ ce_w2,
                       const float* __restrict__ se_w1, const float* __restrict__ se_w2,
                       const float* __restrict__ cd_w1, const float* __restrict__ jd_w1,
                       const float* __restrict__ ce_b1, const float* __restrict__ ce_b2,
                       const float* __restrict__ se_b1, const float* __restrict__ se_b2,
                       const float* __restrict__ cd_g,  const float* __restrict__ cd_bt,
                       const float* __restrict__ cd_b1, const float* __restrict__ jd_g,
                       const float* __restrict__ jd_bt, const float* __restrict__ jd_b1,
                       const float* __restrict__ cd_w2, const float* __restrict__ jd_w2,
                       float* __restrict__ ws){
    char* blob = (char*)ws + BLOB_B;
    const int bid = blockIdx.x, tid = threadIdx.x;
    if (bid < 448){
        // 7 matrices x 16384 elems; m is block-uniform (64 blocks per matrix)
        int e = bid * 256 + tid;
        int m = e >> 14, idx = e & 16383;
        int k = idx >> 7, cc = idx & 127;
        const float* src;
        switch (m){
            case 0: src = ce_w1; break;
            case 1: src = ce_w2; break;
            case 2: src = se_w1; break;
            case 3: src = se_w2; break;
            case 4: src = cd_w1; break;
            case 5: src = jd_w1; break;
            default: src = jd_w1 + 128 * 128; break;
        }
        float v = src[k * 128 + cc];
        int byte = m * 32768 + cc * 256 + ((k << 1) ^ ((cc & 7) << 4));
        *(_Float16*)(blob + byte) = (_Float16)v;
    } else {
        _Float16* p = (_Float16*)((char*)ws + PIMG_B);
        if (tid < 128){
            p[tid]       = (_Float16)ce_b1[tid]; p[128 + tid] = (_Float16)ce_b2[tid];
            p[256 + tid] = (_Float16)se_b1[tid]; p[384 + tid] = (_Float16)se_b2[tid];
            p[512 + tid] = (_Float16)cd_g[tid];  p[640 + tid] = (_Float16)cd_bt[tid];
            p[768 + tid] = (_Float16)cd_b1[tid]; p[896 + tid] = (_Float16)jd_b1[tid];
        } else {
            int i = tid - 128;
            p[1024 + i] = (_Float16)jd_g[i];        p[1152 + i] = (_Float16)jd_g[128 + i];
            p[1280 + i] = (_Float16)jd_bt[i];       p[1408 + i] = (_Float16)jd_bt[128 + i];
            p[1536 + 2*i] = (_Float16)cd_w2[2*i];   p[1537 + 2*i] = (_Float16)cd_w2[2*i+1];
            p[1792 + 2*i] = (_Float16)jd_w2[2*i];   p[1793 + 2*i] = (_Float16)jd_w2[2*i+1];
        }
    }
}

// ======================= stats kernel ======================================
__global__ void k_stats(const int* __restrict__ mask, const int* __restrict__ labels,
                        float* __restrict__ ws){
    int t = blockIdx.x, tid = threadIdx.x;
    float c0 = 0.f, c1 = 0.f;
    for (int b = tid; b < B_; b += 256){
        if (mask[b * T_ + t]){
            if (labels[b] == 1) c1 += 1.f; else c0 += 1.f;
        }
    }
    for (int m = 1; m < 64; m <<= 1){ c0 += __shfl_xor(c0, m); c1 += __shfl_xor(c1, m); }
    __shared__ float sh[8];
    int w = tid >> 6, l = tid & 63;
    if (l == 0){ sh[w] = c0; sh[4 + w] = c1; }
    __syncthreads();
    if (tid == 0){
        float a0 = sh[0] + sh[1] + sh[2] + sh[3];
        float a1 = sh[4] + sh[5] + sh[6] + sh[7];
        float tot = a0 + a1;
        float d = fmaxf(tot, 1.f);
        float p0 = a0 / d, p1 = a1 / d;
        float ent = -(p0 * logf(p0 + 1e-8f) + p1 * logf(p1 + 1e-8f));
        ws[t] = ent;
        ws[64 + t] = (tot >= 2.f) ? 1.f : 0.f;
        ws[128 + t] = tot;
    }
}

// ======================= main fused kernel =================================
// 256 threads (4 waves x 16 rows = 64 rows/block), grid 4096 — the R7 shape:
// LDS 53248 (wbuf 32K + abuf 16K + sp 4K) -> 3 blocks/CU, 12 waves/CU,
// total regs ~148/wave (116 arch + 32 acc) -> 3 waves/SIMD, no spill.
__global__ __launch_bounds__(256, 2) void k_main(
    const float* __restrict__ xc, const float* __restrict__ xs,
    const int* __restrict__ labels, const int* __restrict__ mask,
    const float* __restrict__ cd_b2, const float* __restrict__ jd_b2,
    float* __restrict__ ws, float* __restrict__ out)
{
    __shared__ __align__(16) unsigned short wbuf[128 * 128];    // 32 KB
    __shared__ __align__(16) unsigned short abuf[4 * 16 * 128]; // 16 KB
    __shared__ __align__(16) unsigned short sp[2048];           // 4 KB f16 params

    const int tid = threadIdx.x;
    const int wave = tid >> 6, lane = tid & 63;
    const int c = lane & 15, g = lane >> 4;
    const int wrow0 = blockIdx.x * 64 + wave * 16;
    char* const ab = (char*)abuf + wave * 4096;
    const int lab = labels[(wrow0 + g * 4) >> 6];
    const char* blob = (const char*)ws + BLOB_B;

    f16x8 aX[4], a4[4], cr[4], sr[4], yb[4];
    f32x4 acc[8];
    float ceC[4], ceJ[4];
    float s0c, s1c, mcv, rcv, jmv, jrv;

    // ---- P0: stage params + ce_w1; load xc frags --------------------------
    stage_p((const char*)ws + PIMG_B, (char*)sp, wave, lane);
    stage_w(blob + 0 * 32768, (char*)wbuf, wave, lane);
    load_in(aX, xc + (wrow0 + c) * 128, g);
    __syncthreads();                                            // B1

    const _Float16* sbf = (const _Float16*)sp;

    // ---- P1: enc1 causal ---------------------------------------------------
#pragma unroll
    for (int n = 0; n < 8; n++) acc[n] = (f32x4){0.f,0.f,0.f,0.f};
    mfma_tile(acc, aX, wbuf, c, g);
#pragma unroll
    for (int n = 0; n < 8; n++){
        const int col = n * 16 + c;
        float bi = (float)sbf[col];
#pragma unroll
        for (int rr = 0; rr < 4; rr++){
            float v = gelu_f(acc[n][rr] + bi);
            int row = g * 4 + rr;
            *(_Float16*)(ab + row * 256 + ((col << 1) ^ ((row & 7) << 4))) = (_Float16)v;
        }
    }
    __syncthreads();                                            // B2: ce_w1 retired
    stage_w(blob + 1 * 32768, (char*)wbuf, wave, lane);         // ce_w2
    load_a(a4, ab, c, g);                                       // filler under gll
    __syncthreads();                                            // B3: ce_w2 ready

    // ---- P2: enc2 causal -> c_rep tile ------------------------------------
#pragma unroll
    for (int n = 0; n < 8; n++) acc[n] = (f32x4){0.f,0.f,0.f,0.f};
    mfma_tile(acc, a4, wbuf, c, g);
#pragma unroll
    for (int n = 0; n < 8; n++){
        const int col = n * 16 + c;
        float bi = (float)sbf[128 + col];
#pragma unroll
        for (int rr = 0; rr < 4; rr++){
            int row = g * 4 + rr;
            *(_Float16*)(ab + row * 256 + ((col << 1) ^ ((row & 7) << 4))) = (_Float16)(acc[n][rr] + bi);
        }
    }
    __syncthreads();                                            // B4: c_rep tile ready
    stage_w(blob + 2 * 32768, (char*)wbuf, wave, lane);         // se_w1
    load_a(cr, ab, c, g);                                       // fillers under gll
    {
        s0c = 0.f; s1c = 0.f;
#pragma unroll
        for (int ks = 0; ks < 4; ks++)
#pragma unroll
            for (int j = 0; j < 8; j++){ float v = (float)cr[ks][j]; s0c += v; s1c += v*v; }
        s0c += __shfl_xor(s0c, 16); s0c += __shfl_xor(s0c, 32);
        s1c += __shfl_xor(s1c, 16); s1c += __shfl_xor(s1c, 32);
    }
    load_in(aX, xs + (wrow0 + c) * 128, g);
    __syncthreads();                                            // B5: se_w1 ready

    // ---- P3: enc1 spurious -------------------------------------------------
#pragma unroll
    for (int n = 0; n < 8; n++) acc[n] = (f32x4){0.f,0.f,0.f,0.f};
    mfma_tile(acc, aX, wbuf, c, g);
#pragma unroll
    for (int n = 0; n < 8; n++){
        const int col = n * 16 + c;
        float bi = (float)sbf[256 + col];
#pragma unroll
        for (int rr = 0; rr < 4; rr++){
            float v = gelu_f(acc[n][rr] + bi);
            int row = g * 4 + rr;
            *(_Float16*)(ab + row * 256 + ((col << 1) ^ ((row & 7) << 4))) = (_Float16)v;
        }
    }
    __syncthreads();                                            // B6: se_w1 retired
    stage_w(blob + 3 * 32768, (char*)wbuf, wave, lane);         // se_w2
    load_a(a4, ab, c, g);
    __syncthreads();                                            // B7: se_w2 ready

    // ---- P4: enc2 spurious -> s_rep tile; joint stats ----------------------
#pragma unroll
    for (int n = 0; n < 8; n++) acc[n] = (f32x4){0.f,0.f,0.f,0.f};
    mfma_tile(acc, a4, wbuf, c, g);
#pragma unroll
    for (int n = 0; n < 8; n++){
        const int col = n * 16 + c;
        float bi = (float)sbf[384 + col];
#pragma unroll
        for (int rr = 0; rr < 4; rr++){
            int row = g * 4 + rr;
            *(_Float16*)(ab + row * 256 + ((col << 1) ^ ((row & 7) << 4))) = (_Float16)(acc[n][rr] + bi);
        }
    }
    __syncthreads();                                            // B8: s_rep tile ready
    stage_w(blob + 4 * 32768, (char*)wbuf, wave, lane);         // cd_w1
    load_a(sr, ab, c, g);
    {
        float s0s = 0.f, s1s = 0.f;
#pragma unroll
        for (int ks = 0; ks < 4; ks++)
#pragma unroll
            for (int j = 0; j < 8; j++){ float v = (float)sr[ks][j]; s0s += v; s1s += v*v; }
        s0s += __shfl_xor(s0s, 16); s0s += __shfl_xor(s0s, 32);
        s1s += __shfl_xor(s1s, 16); s1s += __shfl_xor(s1s, 32);
        mcv = s0c * (1.f/128.f);
        rcv = rsqrtf(s1c * (1.f/128.f) - mcv * mcv + 1e-5f);
        jmv = (s0c + s0s) * (1.f/256.f);
        jrv = rsqrtf((s1c + s1s) * (1.f/256.f) - jmv * jmv + 1e-5f);
    }
    __syncthreads();                                            // B9: cd_w1 ready

    // ---- P5: causal decoder (all in-reg) + ceC ----------------------------
    build_y(yb, cr, mcv, rcv, sp, 512, 640, g);
#pragma unroll
    for (int n = 0; n < 8; n++) acc[n] = (f32x4){0.f,0.f,0.f,0.f};
    mfma_tile(acc, yb, wbuf, c, g);
    __syncthreads();                                            // B10: cd_w1 retired
    stage_w(blob + 5 * 32768, (char*)wbuf, wave, lane);         // jd_w1A
    logits_ce(acc, sp, 768, 1536, cd_b2, c, g, lab, ceC);       // filler under gll
    __syncthreads();                                            // B11: jd_w1A ready

    // ---- P6: joint pass A (yjc @ W1A) --------------------------------------
    build_y(yb, cr, jmv, jrv, sp, 1024, 1280, g);
#pragma unroll
    for (int n = 0; n < 8; n++) acc[n] = (f32x4){0.f,0.f,0.f,0.f};
    mfma_tile(acc, yb, wbuf, c, g);
    __syncthreads();                                            // B12: jd_w1A retired
    stage_w(blob + 6 * 32768, (char*)wbuf, wave, lane);         // jd_w1B
    build_y(yb, sr, jmv, jrv, sp, 1152, 1408, g);               // filler under gll
    __syncthreads();                                            // B13: jd_w1B ready

    // ---- P7: joint pass B + ceJ + epilogue ---------------------------------
    mfma_tile(acc, yb, wbuf, c, g);             // accumulate onto pass A
    logits_ce(acc, sp, 896, 1792, jd_b2, c, g, lab, ceJ);

    if (c == 0){
        const int rowbase = wrow0 + g * 4;
        const int4  m4 = *(const int4*)(mask + rowbase);
        const float4 e4 = *(const float4*)(ws + (rowbase & 63));
        const float4 s4 = *(const float4*)(ws + 64 + (rowbase & 63));
        const int   mm[4] = {m4.x, m4.y, m4.z, m4.w};
        const float ee[4] = {e4.x, e4.y, e4.z, e4.w};
        const float sv[4] = {s4.x, s4.y, s4.z, s4.w};
        float rw[4], mc2[4], mj2[4];
#pragma unroll
        for (int rr = 0; rr < 4; rr++){
            float mf = mm[rr] ? 1.f : 0.f;
            float cec = ceC[rr], cej = ceJ[rr];
            rw[rr]  = mf * sv[rr] * (ee[rr] - cec - 0.5f * fmaxf(cec - cej, 0.f));
            mc2[rr] = mf * cec;
            mj2[rr] = mf * cej;
        }
        *(float4*)(out + rowbase)              = (float4){rw[0], rw[1], rw[2], rw[3]};
        *(float4*)(ws + 512 + rowbase)         = (float4){mc2[0], mc2[1], mc2[2], mc2[3]};
        *(float4*)(ws + 512 + NROWS + rowbase) = (float4){mj2[0], mj2[1], mj2[2], mj2[3]};
    }
}

// ======================= aux reductions ====================================
__global__ void k_aux1(float* __restrict__ ws){
    int t = blockIdx.x, tid = threadIdx.x;
    const float* mc = ws + 512;
    const float* mj = ws + 512 + NROWS;
    float sc = 0.f, sj = 0.f;
    for (int b = tid; b < B_; b += 256){ sc += mc[b * T_ + t]; sj += mj[b * T_ + t]; }
    for (int m = 1; m < 64; m <<= 1){ sc += __shfl_xor(sc, m); sj += __shfl_xor(sj, m); }
    __shared__ float sh[8];
    int w = tid >> 6, l = tid & 63;
    if (l == 0){ sh[w] = sc; sh[4 + w] = sj; }
    __syncthreads();
    if (tid == 0){
        float a0 = sh[0] + sh[1] + sh[2] + sh[3];
        float a1 = sh[4] + sh[5] + sh[6] + sh[7];
        ws[192 + t] = ws[64 + t] * 0.5f * (a0 + a1) / fmaxf(ws[128 + t], 1.f);
    }
}

__global__ void k_aux2(const float* __restrict__ ws, float* __restrict__ out){
    int l = threadIdx.x;
    float cv = ws[192 + l], sv = ws[64 + l];
    for (int m = 1; m < 64; m <<= 1){ cv += __shfl_xor(cv, m); sv += __shfl_xor(sv, m); }
    if (l == 0) out[NROWS] = (sv > 0.f) ? cv / fmaxf(sv, 1.f) : 0.f;
}

extern "C" void kernel_launch(void* const* d_in, const int* in_sizes, int n_in,
                              void* d_out, int out_size, void* d_ws, size_t ws_size,
                              hipStream_t stream) {
    const float* xc     = (const float*)d_in[0];
    const float* xs     = (const float*)d_in[1];
    const int*   labels = (const int*)d_in[2];
    const int*   mask   = (const int*)d_in[3];
    const float* ce_w1  = (const float*)d_in[4];
    const float* ce_b1  = (const float*)d_in[5];
    const float* ce_w2  = (const float*)d_in[6];
    const float* ce_b2  = (const float*)d_in[7];
    const float* se_w1  = (const float*)d_in[8];
    const float* se_b1  = (const float*)d_in[9];
    const float* se_w2  = (const float*)d_in[10];
    const float* se_b2  = (const float*)d_in[11];
    const float* cd_g   = (const float*)d_in[12];
    const float* cd_b   = (const float*)d_in[13];
    const float* cd_w1  = (const float*)d_in[14];
    const float* cd_b1  = (const float*)d_in[15];
    const float* cd_w2  = (const float*)d_in[16];
    const float* cd_b2  = (const float*)d_in[17];
    const float* jd_g   = (const float*)d_in[18];
    const float* jd_b   = (const float*)d_in[19];
    const float* jd_w1  = (const float*)d_in[20];
    const float* jd_b1  = (const float*)d_in[21];
    const float* jd_w2  = (const float*)d_in[22];
    const float* jd_b2  = (const float*)d_in[23];
    float* ws  = (float*)d_ws;
    float* out = (float*)d_out;

    k_prep<<<449, 256, 0, stream>>>(ce_w1, ce_w2, se_w1, se_w2, cd_w1, jd_w1,
                                    ce_b1, ce_b2, se_b1, se_b2, cd_g, cd_b,
                                    cd_b1, jd_g, jd_b, jd_b1, cd_w2, jd_w2, ws);
    k_stats<<<64, 256, 0, stream>>>(mask, labels, ws);
    k_main<<<4096, 256, 0, stream>>>(xc, xs, labels, mask, cd_b2, jd_b2, ws, out);
    k_aux1<<<64, 256, 0, stream>>>(ws);
    k_aux2<<<1, 64, 0, stream>>>(ws, out);
}

// Round 14
// 230.596 us; speedup vs baseline: 1.4539x; 1.1567x over previous
//
#include <hip/hip_runtime.h>
#include <hip/hip_fp16.h>

#define B_ 4096
#define T_ 64
#define NROWS (B_*T_)      // 262144
#define BLOB_B 2099200     // byte offset of weight blob in ws (after stats+mc+mj)
#define PIMG_B (BLOB_B + 7*32768)   // param image (4 KB f16)

typedef _Float16 f16x8 __attribute__((ext_vector_type(8)));
typedef float    f32x4 __attribute__((ext_vector_type(4)));

// tanh-form GELU: max |diff| vs exact-erf gelu ~3e-4, ~half the VALU cost of erff
__device__ __forceinline__ float gelu_f(float x){
    float u = 0.7978845608028654f * (x + 0.044715f * x * x * x);
    float t = 1.f - 2.f / (__expf(2.f * u) + 1.f);   // tanh(u)
    return 0.5f * x * (1.f + t);
}

// ---------- async global->LDS, 16B per lane, linear dest ----------
__device__ __forceinline__ void gll16(const void* g, void* l){
    __builtin_amdgcn_global_load_lds(
        (const __attribute__((address_space(1))) void*)g,
        (__attribute__((address_space(3))) void*)l, 16, 0, 0);
}

// stage one 32KB pre-swizzled weight image into wbuf (4 waves x 8 x 1KB)
__device__ __forceinline__ void stage_w(const char* gsrc, char* wbuf, int wave, int lane){
    const char* g = gsrc + wave * 8192 + lane * 16;
    char* l = wbuf + wave * 8192;
#pragma unroll
    for (int r = 0; r < 8; r++) gll16(g + r * 1024, l + r * 1024);
}

// stage 4KB param image (1 issue per wave)
__device__ __forceinline__ void stage_p(const char* gsrc, char* sp, int wave, int lane){
    gll16(gsrc + wave * 1024 + lane * 16, sp + wave * 1024);
}

// ---------- input rows -> f16 A-fragments (K=128 -> 4 frags)
__device__ __forceinline__ void load_in(f16x8* a, const float* __restrict__ p, int g){
#pragma unroll
    for (int ks = 0; ks < 4; ks++){
        const float* q = p + ks * 32 + g * 8;
        float4 v0 = *(const float4*)q, v1 = *(const float4*)(q + 4);
        f16x8 t;
        t[0]=(_Float16)v0.x; t[1]=(_Float16)v0.y; t[2]=(_Float16)v0.z; t[3]=(_Float16)v0.w;
        t[4]=(_Float16)v1.x; t[5]=(_Float16)v1.y; t[6]=(_Float16)v1.z; t[7]=(_Float16)v1.w;
        a[ks] = t;
    }
}

// ---------- A-fragments from wave-private abuf tile [16][128] f16
__device__ __forceinline__ void load_a(f16x8* a, const char* ab, int c, int g){
    const int rswz = (c & 7) << 4;
    const char* rp = ab + c * 256;
#pragma unroll
    for (int ks = 0; ks < 4; ks++)
        a[ks] = *(const f16x8*)(rp + ((ks * 64 + g * 16) ^ rswz));
}

// ---------- full 8-tile MFMA vs staged weights (K=128, row stride 256B)
__device__ __forceinline__ void mfma_tile(f32x4* acc, const f16x8* a,
                                          const unsigned short* wb, int c, int g){
#pragma unroll
    for (int n = 0; n < 8; n++){
        const int r = n * 16 + c;
        const char* rp = (const char*)wb + r * 256;
        const int swz = (r & 7) << 4;
#pragma unroll
        for (int ks = 0; ks < 4; ks++){
            f16x8 b = *(const f16x8*)(rp + ((ks * 64 + g * 16) ^ swz));
            acc[n] = __builtin_amdgcn_mfma_f32_16x16x32_f16(a[ks], b, acc[n], 0, 0, 0);
        }
    }
}

// ---------- epilogue: bias(+gelu) from C-layout acc -> ab tile (scatter u16)
template<bool GELU>
__device__ __forceinline__ void epi_store(const f32x4* acc, char* ab,
                                          const unsigned short* sbh, int boff, int c, int g){
    const _Float16* sbf = (const _Float16*)sbh;
#pragma unroll
    for (int n = 0; n < 8; n++){
        const int col = n * 16 + c;
        float bi = (float)sbf[boff + col];
#pragma unroll
        for (int rr = 0; rr < 4; rr++){
            float v = acc[n][rr] + bi;
            if (GELU) v = gelu_f(v);
            int row = g * 4 + rr;
            *(_Float16*)(ab + row * 256 + ((col << 1) ^ ((row & 7) << 4))) = (_Float16)v;
        }
    }
}

// ---------- LN'd A-fragments in registers
__device__ __forceinline__ void build_y(f16x8* y, const f16x8* x, float mu, float rs,
                                        const unsigned short* sbh, int goff, int boff, int g){
#pragma unroll
    for (int ks = 0; ks < 4; ks++){
        f16x8 gam = *(const f16x8*)((const char*)sbh + goff * 2 + ks * 64 + g * 16);
        f16x8 bet = *(const f16x8*)((const char*)sbh + boff * 2 + ks * 64 + g * 16);
        f16x8 t;
#pragma unroll
        for (int j = 0; j < 8; j++){
            float v = ((float)x[ks][j] - mu) * rs * (float)gam[j] + (float)bet[j];
            t[j] = (_Float16)v;
        }
        y[ks] = t;
    }
}

// ---------- per-row stats over lane's 32 elems + 4-lane-group reduce
__device__ __forceinline__ void row_stats(const f16x8* x, float& s0, float& s1){
    s0 = 0.f; s1 = 0.f;
#pragma unroll
    for (int ks = 0; ks < 4; ks++)
#pragma unroll
        for (int j = 0; j < 8; j++){ float v = (float)x[ks][j]; s0 += v; s1 += v*v; }
    s0 += __shfl_xor(s0, 16); s0 += __shfl_xor(s0, 32);
    s1 += __shfl_xor(s1, 16); s1 += __shfl_xor(s1, 32);
}

// ---------- logits + CE from C-layout acc (shfl-dot over 16 c-lanes)
__device__ __forceinline__ void logits_ce(const f32x4* acc, const unsigned short* sbh,
                                          int b1off, int w2off, const float* __restrict__ b2,
                                          int c, int g, int lab, float* ce){
    const _Float16* sbf = (const _Float16*)sbh;
    float l0[4] = {0,0,0,0}, l1[4] = {0,0,0,0};
#pragma unroll
    for (int n = 0; n < 8; n++){
        const int r = n * 16 + c;
        float b1v = (float)sbf[b1off + r];
        float wx  = (float)sbf[w2off + 2 * r];
        float wy  = (float)sbf[w2off + 2 * r + 1];
#pragma unroll
        for (int rr = 0; rr < 4; rr++){
            float hv = gelu_f(acc[n][rr] + b1v);
            l0[rr] += hv * wx; l1[rr] += hv * wy;
        }
    }
    const float b2x = b2[0], b2y = b2[1];   // load at use: no long-lived regs
#pragma unroll
    for (int rr = 0; rr < 4; rr++){
#pragma unroll
        for (int m = 1; m < 16; m <<= 1){ l0[rr] += __shfl_xor(l0[rr], m); l1[rr] += __shfl_xor(l1[rr], m); }
        float v0 = l0[rr] + b2x, v1 = l1[rr] + b2y;
        float mx = fmaxf(v0, v1);
        float lse = mx + logf(expf(v0 - mx) + expf(v1 - mx));
        ce[rr] = lse - (lab ? v1 : v0);
    }
}

// ======================= prep + stats (merged, 513 blocks) =================
__global__ void k_prep(const float* __restrict__ ce_w1, const float* __restrict__ ce_w2,
                       const float* __restrict__ se_w1, const float* __restrict__ se_w2,
                       const float* __restrict__ cd_w1, const float* __restrict__ jd_w1,
                       const float* __restrict__ ce_b1, const float* __restrict__ ce_b2,
                       const float* __restrict__ se_b1, const float* __restrict__ se_b2,
                       const float* __restrict__ cd_g,  const float* __restrict__ cd_bt,
                       const float* __restrict__ cd_b1, const float* __restrict__ jd_g,
                       const float* __restrict__ jd_bt, const float* __restrict__ jd_b1,
                       const float* __restrict__ cd_w2, const float* __restrict__ jd_w2,
                       const int* __restrict__ mask, const int* __restrict__ labels,
                       float* __restrict__ ws){
    char* blob = (char*)ws + BLOB_B;
    const int bid = blockIdx.x, tid = threadIdx.x;
    if (bid < 448){
        // 7 matrices x 16384 elems; m is block-uniform (64 blocks per matrix)
        int e = bid * 256 + tid;
        int m = e >> 14, idx = e & 16383;
        int k = idx >> 7, cc = idx & 127;
        const float* src;
        switch (m){
            case 0: src = ce_w1; break;
            case 1: src = ce_w2; break;
            case 2: src = se_w1; break;
            case 3: src = se_w2; break;
            case 4: src = cd_w1; break;
            case 5: src = jd_w1; break;
            default: src = jd_w1 + 128 * 128; break;
        }
        float v = src[k * 128 + cc];
        int byte = m * 32768 + cc * 256 + ((k << 1) ^ ((cc & 7) << 4));
        *(_Float16*)(blob + byte) = (_Float16)v;
    } else if (bid < 512){
        // stats for t = bid-448
        int t = bid - 448;
        float c0 = 0.f, c1 = 0.f;
        for (int b = tid; b < B_; b += 256){
            if (mask[b * T_ + t]){
                if (labels[b] == 1) c1 += 1.f; else c0 += 1.f;
            }
        }
        for (int m = 1; m < 64; m <<= 1){ c0 += __shfl_xor(c0, m); c1 += __shfl_xor(c1, m); }
        __shared__ float sh[8];
        int w = tid >> 6, l = tid & 63;
        if (l == 0){ sh[w] = c0; sh[4 + w] = c1; }
        __syncthreads();
        if (tid == 0){
            float a0 = sh[0] + sh[1] + sh[2] + sh[3];
            float a1 = sh[4] + sh[5] + sh[6] + sh[7];
            float tot = a0 + a1;
            float d = fmaxf(tot, 1.f);
            float p0 = a0 / d, p1 = a1 / d;
            float ent = -(p0 * logf(p0 + 1e-8f) + p1 * logf(p1 + 1e-8f));
            ws[t] = ent;
            ws[64 + t] = (tot >= 2.f) ? 1.f : 0.f;
            ws[128 + t] = tot;
        }
    } else {
        _Float16* p = (_Float16*)((char*)ws + PIMG_B);
        if (tid < 128){
            p[tid]       = (_Float16)ce_b1[tid]; p[128 + tid] = (_Float16)ce_b2[tid];
            p[256 + tid] = (_Float16)se_b1[tid]; p[384 + tid] = (_Float16)se_b2[tid];
            p[512 + tid] = (_Float16)cd_g[tid];  p[640 + tid] = (_Float16)cd_bt[tid];
            p[768 + tid] = (_Float16)cd_b1[tid]; p[896 + tid] = (_Float16)jd_b1[tid];
        } else {
            int i = tid - 128;
            p[1024 + i] = (_Float16)jd_g[i];        p[1152 + i] = (_Float16)jd_g[128 + i];
            p[1280 + i] = (_Float16)jd_bt[i];       p[1408 + i] = (_Float16)jd_bt[128 + i];
            p[1536 + 2*i] = (_Float16)cd_w2[2*i];   p[1537 + 2*i] = (_Float16)cd_w2[2*i+1];
            p[1792 + 2*i] = (_Float16)jd_w2[2*i];   p[1793 + 2*i] = (_Float16)jd_w2[2*i+1];
        }
    }
}

// ======================= main fused kernel =================================
// R13 shape (256 thd, 53 KB LDS, 96+32 regs) with epilogue-under-stage:
// retire barrier moved to right after each mfma; the bias/gelu/scatter
// epilogue runs under the in-flight global_load_lds of the next matrix.
__global__ __launch_bounds__(256, 2) void k_main(
    const float* __restrict__ xc, const float* __restrict__ xs,
    const int* __restrict__ labels, const int* __restrict__ mask,
    const float* __restrict__ cd_b2, const float* __restrict__ jd_b2,
    float* __restrict__ ws, float* __restrict__ out)
{
    __shared__ __align__(16) unsigned short wbuf[128 * 128];    // 32 KB
    __shared__ __align__(16) unsigned short abuf[4 * 16 * 128]; // 16 KB
    __shared__ __align__(16) unsigned short sp[2048];           // 4 KB f16 params

    const int tid = threadIdx.x;
    const int wave = tid >> 6, lane = tid & 63;
    const int c = lane & 15, g = lane >> 4;
    const int wrow0 = blockIdx.x * 64 + wave * 16;
    char* const ab = (char*)abuf + wave * 4096;
    const int lab = labels[(wrow0 + g * 4) >> 6];
    const char* blob = (const char*)ws + BLOB_B;

    f16x8 aX[4], a4[4], cr[4], sr[4], yb[4];
    f32x4 acc[8];
    float ceC[4], ceJ[4];
    float s0c, s1c, mcv, rcv, jmv, jrv;

    // ---- P0: stage params + ce_w1; load xc frags --------------------------
    stage_p((const char*)ws + PIMG_B, (char*)sp, wave, lane);
    stage_w(blob + 0 * 32768, (char*)wbuf, wave, lane);
    load_in(aX, xc + (wrow0 + c) * 128, g);
    __syncthreads();                                            // B1: m0+sp ready

    // ---- P1: enc1 causal ---------------------------------------------------
#pragma unroll
    for (int n = 0; n < 8; n++) acc[n] = (f32x4){0.f,0.f,0.f,0.f};
    mfma_tile(acc, aX, wbuf, c, g);
    __syncthreads();                                            // B2: m0 retired
    stage_w(blob + 1 * 32768, (char*)wbuf, wave, lane);         // ce_w2
    epi_store<true>(acc, ab, sp, 0, c, g);                      // gelu epi under gll
    __syncthreads();                                            // B3: m1 + ab ready

    // ---- P2: enc2 causal -> c_rep tile ------------------------------------
    load_a(a4, ab, c, g);
#pragma unroll
    for (int n = 0; n < 8; n++) acc[n] = (f32x4){0.f,0.f,0.f,0.f};
    mfma_tile(acc, a4, wbuf, c, g);
    __syncthreads();                                            // B4: m1 retired
    stage_w(blob + 2 * 32768, (char*)wbuf, wave, lane);         // se_w1
    epi_store<false>(acc, ab, sp, 128, c, g);                   // c_rep epi under gll
    load_in(aX, xs + (wrow0 + c) * 128, g);                     // xs prefetch
    __syncthreads();                                            // B5: m2 + ab ready

    // ---- P3: enc1 spurious -------------------------------------------------
    load_a(cr, ab, c, g);                                       // c_rep frags
#pragma unroll
    for (int n = 0; n < 8; n++) acc[n] = (f32x4){0.f,0.f,0.f,0.f};
    mfma_tile(acc, aX, wbuf, c, g);
    __syncthreads();                                            // B6: m2 retired, cr read done
    stage_w(blob + 3 * 32768, (char*)wbuf, wave, lane);         // se_w2
    epi_store<true>(acc, ab, sp, 256, c, g);                    // gelu epi under gll
    row_stats(cr, s0c, s1c);                                    // extra filler
    __syncthreads();                                            // B7: m3 + ab ready

    // ---- P4: enc2 spurious -> s_rep tile -----------------------------------
    load_a(a4, ab, c, g);
#pragma unroll
    for (int n = 0; n < 8; n++) acc[n] = (f32x4){0.f,0.f,0.f,0.f};
    mfma_tile(acc, a4, wbuf, c, g);
    __syncthreads();                                            // B8: m3 retired
    stage_w(blob + 4 * 32768, (char*)wbuf, wave, lane);         // cd_w1
    epi_store<false>(acc, ab, sp, 384, c, g);                   // s_rep epi under gll
    __syncthreads();                                            // B9: m4 + ab ready

    // ---- P5: causal decoder (all in-reg) + ceC ----------------------------
    load_a(sr, ab, c, g);
    {
        float s0s, s1s;
        row_stats(sr, s0s, s1s);
        mcv = s0c * (1.f/128.f);
        rcv = rsqrtf(s1c * (1.f/128.f) - mcv * mcv + 1e-5f);
        jmv = (s0c + s0s) * (1.f/256.f);
        jrv = rsqrtf((s1c + s1s) * (1.f/256.f) - jmv * jmv + 1e-5f);
    }
    build_y(yb, cr, mcv, rcv, sp, 512, 640, g);
#pragma unroll
    for (int n = 0; n < 8; n++) acc[n] = (f32x4){0.f,0.f,0.f,0.f};
    mfma_tile(acc, yb, wbuf, c, g);
    __syncthreads();                                            // B10: m4 retired
    stage_w(blob + 5 * 32768, (char*)wbuf, wave, lane);         // jd_w1A
    logits_ce(acc, sp, 768, 1536, cd_b2, c, g, lab, ceC);       // filler under gll
    build_y(yb, cr, jmv, jrv, sp, 1024, 1280, g);               // yjc frags (cr dies)
    __syncthreads();                                            // B11: m5 ready

    // ---- P6: joint pass A (yjc @ W1A) --------------------------------------
#pragma unroll
    for (int n = 0; n < 8; n++) acc[n] = (f32x4){0.f,0.f,0.f,0.f};
    mfma_tile(acc, yb, wbuf, c, g);
    __syncthreads();                                            // B12: m5 retired
    stage_w(blob + 6 * 32768, (char*)wbuf, wave, lane);         // jd_w1B
    build_y(yb, sr, jmv, jrv, sp, 1152, 1408, g);               // yjs frags (sr dies)
    __syncthreads();                                            // B13: m6 ready

    // ---- P7: joint pass B + ceJ + epilogue ---------------------------------
    mfma_tile(acc, yb, wbuf, c, g);             // accumulate onto pass A
    logits_ce(acc, sp, 896, 1792, jd_b2, c, g, lab, ceJ);

    if (c == 0){
        const int rowbase = wrow0 + g * 4;
        const int4  m4 = *(const int4*)(mask + rowbase);
        const float4 e4 = *(const float4*)(ws + (rowbase & 63));
        const float4 s4 = *(const float4*)(ws + 64 + (rowbase & 63));
        const int   mm[4] = {m4.x, m4.y, m4.z, m4.w};
        const float ee[4] = {e4.x, e4.y, e4.z, e4.w};
        const float sv[4] = {s4.x, s4.y, s4.z, s4.w};
        float rw[4], mc2[4], mj2[4];
#pragma unroll
        for (int rr = 0; rr < 4; rr++){
            float mf = mm[rr] ? 1.f : 0.f;
            float cec = ceC[rr], cej = ceJ[rr];
            rw[rr]  = mf * sv[rr] * (ee[rr] - cec - 0.5f * fmaxf(cec - cej, 0.f));
            mc2[rr] = mf * cec;
            mj2[rr] = mf * cej;
        }
        *(float4*)(out + rowbase)              = (float4){rw[0], rw[1], rw[2], rw[3]};
        *(float4*)(ws + 512 + rowbase)         = (float4){mc2[0], mc2[1], mc2[2], mc2[3]};
        *(float4*)(ws + 512 + NROWS + rowbase) = (float4){mj2[0], mj2[1], mj2[2], mj2[3]};
    }
}

// ======================= aux reductions ====================================
__global__ void k_aux1(float* __restrict__ ws){
    int t = blockIdx.x, tid = threadIdx.x;
    const float* mc = ws + 512;
    const float* mj = ws + 512 + NROWS;
    float sc = 0.f, sj = 0.f;
    for (int b = tid; b < B_; b += 256){ sc += mc[b * T_ + t]; sj += mj[b * T_ + t]; }
    for (int m = 1; m < 64; m <<= 1){ sc += __shfl_xor(sc, m); sj += __shfl_xor(sj, m); }
    __shared__ float sh[8];
    int w = tid >> 6, l = tid & 63;
    if (l == 0){ sh[w] = sc; sh[4 + w] = sj; }
    __syncthreads();
    if (tid == 0){
        float a0 = sh[0] + sh[1] + sh[2] + sh[3];
        float a1 = sh[4] + sh[5] + sh[6] + sh[7];
        ws[192 + t] = ws[64 + t] * 0.5f * (a0 + a1) / fmaxf(ws[128 + t], 1.f);
    }
}

__global__ void k_aux2(const float* __restrict__ ws, float* __restrict__ out){
    int l = threadIdx.x;
    float cv = ws[192 + l], sv = ws[64 + l];
    for (int m = 1; m < 64; m <<= 1){ cv += __shfl_xor(cv, m); sv += __shfl_xor(sv, m); }
    if (l == 0) out[NROWS] = (sv > 0.f) ? cv / fmaxf(sv, 1.f) : 0.f;
}

extern "C" void kernel_launch(void* const* d_in, const int* in_sizes, int n_in,
                              void* d_out, int out_size, void* d_ws, size_t ws_size,
                              hipStream_t stream) {
    const float* xc     = (const float*)d_in[0];
    const float* xs     = (const float*)d_in[1];
    const int*   labels = (const int*)d_in[2];
    const int*   mask   = (const int*)d_in[3];
    const float* ce_w1  = (const float*)d_in[4];
    const float* ce_b1  = (const float*)d_in[5];
    const float* ce_w2  = (const float*)d_in[6];
    const float* ce_b2  = (const float*)d_in[7];
    const float* se_w1  = (const float*)d_in[8];
    const float* se_b1  = (const float*)d_in[9];
    const float* se_w2  = (const float*)d_in[10];
    const float* se_b2  = (const float*)d_in[11];
    const float* cd_g   = (const float*)d_in[12];
    const float* cd_b   = (const float*)d_in[13];
    const float* cd_w1  = (const float*)d_in[14];
    const float* cd_b1  = (const float*)d_in[15];
    const float* cd_w2  = (const float*)d_in[16];
    const float* cd_b2  = (const float*)d_in[17];
    const float* jd_g   = (const float*)d_in[18];
    const float* jd_b   = (const float*)d_in[19];
    const float* jd_w1  = (const float*)d_in[20];
    const float* jd_b1  = (const float*)d_in[21];
    const float* jd_w2  = (const float*)d_in[22];
    const float* jd_b2  = (const float*)d_in[23];
    float* ws  = (float*)d_ws;
    float* out = (float*)d_out;

    k_prep<<<513, 256, 0, stream>>>(ce_w1, ce_w2, se_w1, se_w2, cd_w1, jd_w1,
                                    ce_b1, ce_b2, se_b1, se_b2, cd_g, cd_b,
                                    cd_b1, jd_g, jd_b, jd_b1, cd_w2, jd_w2,
                                    mask, labels, ws);
    k_main<<<4096, 256, 0, stream>>>(xc, xs, labels, mask, cd_b2, jd_b2, ws, out);
    k_aux1<<<64, 256, 0, stream>>>(ws);
    k_aux2<<<1, 64, 0, stream>>>(ws, out);
}

// Round 15
// 229.041 us; speedup vs baseline: 1.4637x; 1.0068x over previous
//
#include <hip/hip_runtime.h>
#include <hip/hip_fp16.h>

#define B_ 4096
#define T_ 64
#define NROWS (B_*T_)      // 262144
#define BLOB_B 2099200     // byte offset of weight blob in ws (after stats+mc+mj)
#define PIMG_B (BLOB_B + 7*32768)   // param image (4 KB f16)

typedef _Float16 f16x8 __attribute__((ext_vector_type(8)));
typedef float    f32x4 __attribute__((ext_vector_type(4)));

// tanh-form GELU: max |diff| vs exact-erf gelu ~3e-4, ~half the VALU cost of erff
__device__ __forceinline__ float gelu_f(float x){
    float u = 0.7978845608028654f * (x + 0.044715f * x * x * x);
    float t = 1.f - 2.f / (__expf(2.f * u) + 1.f);   // tanh(u)
    return 0.5f * x * (1.f + t);
}

// ---------- async global->LDS, 16B per lane, linear dest ----------
__device__ __forceinline__ void gll16(const void* g, void* l){
    __builtin_amdgcn_global_load_lds(
        (const __attribute__((address_space(1))) void*)g,
        (__attribute__((address_space(3))) void*)l, 16, 0, 0);
}

// stage one 32KB pre-swizzled weight image into wbuf (4 waves x 8 x 1KB)
__device__ __forceinline__ void stage_w(const char* gsrc, char* wbuf, int wave, int lane){
    const char* g = gsrc + wave * 8192 + lane * 16;
    char* l = wbuf + wave * 8192;
#pragma unroll
    for (int r = 0; r < 8; r++) gll16(g + r * 1024, l + r * 1024);
}

// stage 4KB param image (1 issue per wave)
__device__ __forceinline__ void stage_p(const char* gsrc, char* sp, int wave, int lane){
    gll16(gsrc + wave * 1024 + lane * 16, sp + wave * 1024);
}

// ---------- input rows -> f16 A-fragments (K=128 -> 4 frags)
__device__ __forceinline__ void load_in(f16x8* a, const float* __restrict__ p, int g){
#pragma unroll
    for (int ks = 0; ks < 4; ks++){
        const float* q = p + ks * 32 + g * 8;
        float4 v0 = *(const float4*)q, v1 = *(const float4*)(q + 4);
        f16x8 t;
        t[0]=(_Float16)v0.x; t[1]=(_Float16)v0.y; t[2]=(_Float16)v0.z; t[3]=(_Float16)v0.w;
        t[4]=(_Float16)v1.x; t[5]=(_Float16)v1.y; t[6]=(_Float16)v1.z; t[7]=(_Float16)v1.w;
        a[ks] = t;
    }
}

// ---------- A-fragments from wave-private abuf tile [16][128] f16
// ab layout: byte(row,col) = row*256 + ((col*2) ^ ((row>>2)<<5))
// S multiple of 32 -> 16B fragment contiguity + element order preserved.
__device__ __forceinline__ void load_a(f16x8* a, const char* ab, int c, int g){
    const int rswz = (c & 12) << 3;     // (c>>2)<<5
    const char* rp = ab + c * 256;
#pragma unroll
    for (int ks = 0; ks < 4; ks++)
        a[ks] = *(const f16x8*)(rp + ((ks * 64 + g * 16) ^ rswz));
}

// ---------- full 8-tile MFMA vs staged weights (K=128, row stride 256B)
// wbuf keeps the ORIGINAL prep swizzle ((cc&7)<<4) — unchanged.
__device__ __forceinline__ void mfma_tile(f32x4* acc, const f16x8* a,
                                          const unsigned short* wb, int c, int g){
#pragma unroll
    for (int n = 0; n < 8; n++){
        const int r = n * 16 + c;
        const char* rp = (const char*)wb + r * 256;
        const int swz = (r & 7) << 4;
#pragma unroll
        for (int ks = 0; ks < 4; ks++){
            f16x8 b = *(const f16x8*)(rp + ((ks * 64 + g * 16) ^ swz));
            acc[n] = __builtin_amdgcn_mfma_f32_16x16x32_f16(a[ks], b, acc[n], 0, 0, 0);
        }
    }
}

// ---------- epilogue: bias(+gelu) from C-layout acc -> ab tile
// store swizzle S = g<<5 (lane-constant): per-(n,rr) store windows (n^g)*32
// are disjoint across g-groups -> conflict-free LDS writes.
template<bool GELU>
__device__ __forceinline__ void epi_store(const f32x4* acc, char* ab,
                                          const unsigned short* sbh, int boff, int c, int g){
    const _Float16* sbf = (const _Float16*)sbh;
    const int swz = g << 5;
#pragma unroll
    for (int n = 0; n < 8; n++){
        const int col = n * 16 + c;
        float bi = (float)sbf[boff + col];
#pragma unroll
        for (int rr = 0; rr < 4; rr++){
            float v = acc[n][rr] + bi;
            if (GELU) v = gelu_f(v);
            int row = g * 4 + rr;
            *(_Float16*)(ab + row * 256 + ((col << 1) ^ swz)) = (_Float16)v;
        }
    }
}

// ---------- LN'd A-fragments in registers
__device__ __forceinline__ void build_y(f16x8* y, const f16x8* x, float mu, float rs,
                                        const unsigned short* sbh, int goff, int boff, int g){
#pragma unroll
    for (int ks = 0; ks < 4; ks++){
        f16x8 gam = *(const f16x8*)((const char*)sbh + goff * 2 + ks * 64 + g * 16);
        f16x8 bet = *(const f16x8*)((const char*)sbh + boff * 2 + ks * 64 + g * 16);
        f16x8 t;
#pragma unroll
        for (int j = 0; j < 8; j++){
            float v = ((float)x[ks][j] - mu) * rs * (float)gam[j] + (float)bet[j];
            t[j] = (_Float16)v;
        }
        y[ks] = t;
    }
}

// ---------- per-row stats over lane's 32 elems + 4-lane-group reduce
__device__ __forceinline__ void row_stats(const f16x8* x, float& s0, float& s1){
    s0 = 0.f; s1 = 0.f;
#pragma unroll
    for (int ks = 0; ks < 4; ks++)
#pragma unroll
        for (int j = 0; j < 8; j++){ float v = (float)x[ks][j]; s0 += v; s1 += v*v; }
    s0 += __shfl_xor(s0, 16); s0 += __shfl_xor(s0, 32);
    s1 += __shfl_xor(s1, 16); s1 += __shfl_xor(s1, 32);
}

// ---------- logits + CE from C-layout acc (shfl-dot over 16 c-lanes)
__device__ __forceinline__ void logits_ce(const f32x4* acc, const unsigned short* sbh,
                                          int b1off, int w2off, const float* __restrict__ b2,
                                          int c, int g, int lab, float* ce){
    const _Float16* sbf = (const _Float16*)sbh;
    float l0[4] = {0,0,0,0}, l1[4] = {0,0,0,0};
#pragma unroll
    for (int n = 0; n < 8; n++){
        const int r = n * 16 + c;
        float b1v = (float)sbf[b1off + r];
        float wx  = (float)sbf[w2off + 2 * r];
        float wy  = (float)sbf[w2off + 2 * r + 1];
#pragma unroll
        for (int rr = 0; rr < 4; rr++){
            float hv = gelu_f(acc[n][rr] + b1v);
            l0[rr] += hv * wx; l1[rr] += hv * wy;
        }
    }
    const float b2x = b2[0], b2y = b2[1];   // load at use: no long-lived regs
#pragma unroll
    for (int rr = 0; rr < 4; rr++){
#pragma unroll
        for (int m = 1; m < 16; m <<= 1){ l0[rr] += __shfl_xor(l0[rr], m); l1[rr] += __shfl_xor(l1[rr], m); }
        float v0 = l0[rr] + b2x, v1 = l1[rr] + b2y;
        float mx = fmaxf(v0, v1);
        float lse = mx + __logf(__expf(v0 - mx) + __expf(v1 - mx));
        ce[rr] = lse - (lab ? v1 : v0);
    }
}

// ======================= prep + stats (merged, 513 blocks) =================
__global__ void k_prep(const float* __restrict__ ce_w1, const float* __restrict__ ce_w2,
                       const float* __restrict__ se_w1, const float* __restrict__ se_w2,
                       const float* __restrict__ cd_w1, const float* __restrict__ jd_w1,
                       const float* __restrict__ ce_b1, const float* __restrict__ ce_b2,
                       const float* __restrict__ se_b1, const float* __restrict__ se_b2,
                       const float* __restrict__ cd_g,  const float* __restrict__ cd_bt,
                       const float* __restrict__ cd_b1, const float* __restrict__ jd_g,
                       const float* __restrict__ jd_bt, const float* __restrict__ jd_b1,
                       const float* __restrict__ cd_w2, const float* __restrict__ jd_w2,
                       const int* __restrict__ mask, const int* __restrict__ labels,
                       float* __restrict__ ws){
    char* blob = (char*)ws + BLOB_B;
    const int bid = blockIdx.x, tid = threadIdx.x;
    if (bid < 448){
        // 7 matrices x 16384 elems; m is block-uniform (64 blocks per matrix)
        int e = bid * 256 + tid;
        int m = e >> 14, idx = e & 16383;
        int k = idx >> 7, cc = idx & 127;
        const float* src;
        switch (m){
            case 0: src = ce_w1; break;
            case 1: src = ce_w2; break;
            case 2: src = se_w1; break;
            case 3: src = se_w2; break;
            case 4: src = cd_w1; break;
            case 5: src = jd_w1; break;
            default: src = jd_w1 + 128 * 128; break;
        }
        float v = src[k * 128 + cc];
        int byte = m * 32768 + cc * 256 + ((k << 1) ^ ((cc & 7) << 4));
        *(_Float16*)(blob + byte) = (_Float16)v;
    } else if (bid < 512){
        // stats for t = bid-448
        int t = bid - 448;
        float c0 = 0.f, c1 = 0.f;
        for (int b = tid; b < B_; b += 256){
            if (mask[b * T_ + t]){
                if (labels[b] == 1) c1 += 1.f; else c0 += 1.f;
            }
        }
        for (int m = 1; m < 64; m <<= 1){ c0 += __shfl_xor(c0, m); c1 += __shfl_xor(c1, m); }
        __shared__ float sh[8];
        int w = tid >> 6, l = tid & 63;
        if (l == 0){ sh[w] = c0; sh[4 + w] = c1; }
        __syncthreads();
        if (tid == 0){
            float a0 = sh[0] + sh[1] + sh[2] + sh[3];
            float a1 = sh[4] + sh[5] + sh[6] + sh[7];
            float tot = a0 + a1;
            float d = fmaxf(tot, 1.f);
            float p0 = a0 / d, p1 = a1 / d;
            float ent = -(p0 * logf(p0 + 1e-8f) + p1 * logf(p1 + 1e-8f));
            ws[t] = ent;
            ws[64 + t] = (tot >= 2.f) ? 1.f : 0.f;
            ws[128 + t] = tot;
        }
    } else {
        _Float16* p = (_Float16*)((char*)ws + PIMG_B);
        if (tid < 128){
            p[tid]       = (_Float16)ce_b1[tid]; p[128 + tid] = (_Float16)ce_b2[tid];
            p[256 + tid] = (_Float16)se_b1[tid]; p[384 + tid] = (_Float16)se_b2[tid];
            p[512 + tid] = (_Float16)cd_g[tid];  p[640 + tid] = (_Float16)cd_bt[tid];
            p[768 + tid] = (_Float16)cd_b1[tid]; p[896 + tid] = (_Float16)jd_b1[tid];
        } else {
            int i = tid - 128;
            p[1024 + i] = (_Float16)jd_g[i];        p[1152 + i] = (_Float16)jd_g[128 + i];
            p[1280 + i] = (_Float16)jd_bt[i];       p[1408 + i] = (_Float16)jd_bt[128 + i];
            p[1536 + 2*i] = (_Float16)cd_w2[2*i];   p[1537 + 2*i] = (_Float16)cd_w2[2*i+1];
            p[1792 + 2*i] = (_Float16)jd_w2[2*i];   p[1793 + 2*i] = (_Float16)jd_w2[2*i+1];
        }
    }
}

// ======================= main fused kernel =================================
// R14 structure (256 thd, 53 KB LDS, epilogue-under-stage) with the
// conflict-free epilogue swizzle S=g<<5 on the ab tiles.
__global__ __launch_bounds__(256, 2) void k_main(
    const float* __restrict__ xc, const float* __restrict__ xs,
    const int* __restrict__ labels, const int* __restrict__ mask,
    const float* __restrict__ cd_b2, const float* __restrict__ jd_b2,
    float* __restrict__ ws, float* __restrict__ out)
{
    __shared__ __align__(16) unsigned short wbuf[128 * 128];    // 32 KB
    __shared__ __align__(16) unsigned short abuf[4 * 16 * 128]; // 16 KB
    __shared__ __align__(16) unsigned short sp[2048];           // 4 KB f16 params

    const int tid = threadIdx.x;
    const int wave = tid >> 6, lane = tid & 63;
    const int c = lane & 15, g = lane >> 4;
    const int wrow0 = blockIdx.x * 64 + wave * 16;
    char* const ab = (char*)abuf + wave * 4096;
    const int lab = labels[(wrow0 + g * 4) >> 6];
    const char* blob = (const char*)ws + BLOB_B;

    f16x8 aX[4], a4[4], cr[4], sr[4], yb[4];
    f32x4 acc[8];
    float ceC[4], ceJ[4];
    float s0c, s1c, mcv, rcv, jmv, jrv;

    // ---- P0: stage params + ce_w1; load xc frags --------------------------
    stage_p((const char*)ws + PIMG_B, (char*)sp, wave, lane);
    stage_w(blob + 0 * 32768, (char*)wbuf, wave, lane);
    load_in(aX, xc + (wrow0 + c) * 128, g);
    __syncthreads();                                            // B1: m0+sp ready

    // ---- P1: enc1 causal ---------------------------------------------------
#pragma unroll
    for (int n = 0; n < 8; n++) acc[n] = (f32x4){0.f,0.f,0.f,0.f};
    mfma_tile(acc, aX, wbuf, c, g);
    __syncthreads();                                            // B2: m0 retired
    stage_w(blob + 1 * 32768, (char*)wbuf, wave, lane);         // ce_w2
    epi_store<true>(acc, ab, sp, 0, c, g);                      // gelu epi under gll
    __syncthreads();                                            // B3: m1 + ab ready

    // ---- P2: enc2 causal -> c_rep tile ------------------------------------
    load_a(a4, ab, c, g);
#pragma unroll
    for (int n = 0; n < 8; n++) acc[n] = (f32x4){0.f,0.f,0.f,0.f};
    mfma_tile(acc, a4, wbuf, c, g);
    __syncthreads();                                            // B4: m1 retired
    stage_w(blob + 2 * 32768, (char*)wbuf, wave, lane);         // se_w1
    epi_store<false>(acc, ab, sp, 128, c, g);                   // c_rep epi under gll
    load_in(aX, xs + (wrow0 + c) * 128, g);                     // xs prefetch
    __syncthreads();                                            // B5: m2 + ab ready

    // ---- P3: enc1 spurious -------------------------------------------------
    load_a(cr, ab, c, g);                                       // c_rep frags
#pragma unroll
    for (int n = 0; n < 8; n++) acc[n] = (f32x4){0.f,0.f,0.f,0.f};
    mfma_tile(acc, aX, wbuf, c, g);
    __syncthreads();                                            // B6: m2 retired, cr read done
    stage_w(blob + 3 * 32768, (char*)wbuf, wave, lane);         // se_w2
    epi_store<true>(acc, ab, sp, 256, c, g);                    // gelu epi under gll
    row_stats(cr, s0c, s1c);                                    // extra filler
    __syncthreads();                                            // B7: m3 + ab ready

    // ---- P4: enc2 spurious -> s_rep tile -----------------------------------
    load_a(a4, ab, c, g);
#pragma unroll
    for (int n = 0; n < 8; n++) acc[n] = (f32x4){0.f,0.f,0.f,0.f};
    mfma_tile(acc, a4, wbuf, c, g);
    __syncthreads();                                            // B8: m3 retired
    stage_w(blob + 4 * 32768, (char*)wbuf, wave, lane);         // cd_w1
    epi_store<false>(acc, ab, sp, 384, c, g);                   // s_rep epi under gll
    __syncthreads();                                            // B9: m4 + ab ready

    // ---- P5: causal decoder (all in-reg) + ceC ----------------------------
    load_a(sr, ab, c, g);
    {
        float s0s, s1s;
        row_stats(sr, s0s, s1s);
        mcv = s0c * (1.f/128.f);
        rcv = rsqrtf(s1c * (1.f/128.f) - mcv * mcv + 1e-5f);
        jmv = (s0c + s0s) * (1.f/256.f);
        jrv = rsqrtf((s1c + s1s) * (1.f/256.f) - jmv * jmv + 1e-5f);
    }
    build_y(yb, cr, mcv, rcv, sp, 512, 640, g);
#pragma unroll
    for (int n = 0; n < 8; n++) acc[n] = (f32x4){0.f,0.f,0.f,0.f};
    mfma_tile(acc, yb, wbuf, c, g);
    __syncthreads();                                            // B10: m4 retired
    stage_w(blob + 5 * 32768, (char*)wbuf, wave, lane);         // jd_w1A
    logits_ce(acc, sp, 768, 1536, cd_b2, c, g, lab, ceC);       // filler under gll
    build_y(yb, cr, jmv, jrv, sp, 1024, 1280, g);               // yjc frags (cr dies)
    __syncthreads();                                            // B11: m5 ready

    // ---- P6: joint pass A (yjc @ W1A) --------------------------------------
#pragma unroll
    for (int n = 0; n < 8; n++) acc[n] = (f32x4){0.f,0.f,0.f,0.f};
    mfma_tile(acc, yb, wbuf, c, g);
    __syncthreads();                                            // B12: m5 retired
    stage_w(blob + 6 * 32768, (char*)wbuf, wave, lane);         // jd_w1B
    build_y(yb, sr, jmv, jrv, sp, 1152, 1408, g);               // yjs frags (sr dies)
    __syncthreads();                                            // B13: m6 ready

    // ---- P7: joint pass B + ceJ + epilogue ---------------------------------
    mfma_tile(acc, yb, wbuf, c, g);             // accumulate onto pass A
    logits_ce(acc, sp, 896, 1792, jd_b2, c, g, lab, ceJ);

    if (c == 0){
        const int rowbase = wrow0 + g * 4;
        const int4  m4 = *(const int4*)(mask + rowbase);
        const float4 e4 = *(const float4*)(ws + (rowbase & 63));
        const float4 s4 = *(const float4*)(ws + 64 + (rowbase & 63));
        const int   mm[4] = {m4.x, m4.y, m4.z, m4.w};
        const float ee[4] = {e4.x, e4.y, e4.z, e4.w};
        const float sv[4] = {s4.x, s4.y, s4.z, s4.w};
        float rw[4], mc2[4], mj2[4];
#pragma unroll
        for (int rr = 0; rr < 4; rr++){
            float mf = mm[rr] ? 1.f : 0.f;
            float cec = ceC[rr], cej = ceJ[rr];
            rw[rr]  = mf * sv[rr] * (ee[rr] - cec - 0.5f * fmaxf(cec - cej, 0.f));
            mc2[rr] = mf * cec;
            mj2[rr] = mf * cej;
        }
        *(float4*)(out + rowbase)              = (float4){rw[0], rw[1], rw[2], rw[3]};
        *(float4*)(ws + 512 + rowbase)         = (float4){mc2[0], mc2[1], mc2[2], mc2[3]};
        *(float4*)(ws + 512 + NROWS + rowbase) = (float4){mj2[0], mj2[1], mj2[2], mj2[3]};
    }
}

// ======================= aux reductions ====================================
__global__ void k_aux1(float* __restrict__ ws){
    int t = blockIdx.x, tid = threadIdx.x;
    const float* mc = ws + 512;
    const float* mj = ws + 512 + NROWS;
    float sc = 0.f, sj = 0.f;
    for (int b = tid; b < B_; b += 256){ sc += mc[b * T_ + t]; sj += mj[b * T_ + t]; }
    for (int m = 1; m < 64; m <<= 1){ sc += __shfl_xor(sc, m); sj += __shfl_xor(sj, m); }
    __shared__ float sh[8];
    int w = tid >> 6, l = tid & 63;
    if (l == 0){ sh[w] = sc; sh[4 + w] = sj; }
    __syncthreads();
    if (tid == 0){
        float a0 = sh[0] + sh[1] + sh[2] + sh[3];
        float a1 = sh[4] + sh[5] + sh[6] + sh[7];
        ws[192 + t] = ws[64 + t] * 0.5f * (a0 + a1) / fmaxf(ws[128 + t], 1.f);
    }
}

__global__ void k_aux2(const float* __restrict__ ws, float* __restrict__ out){
    int l = threadIdx.x;
    float cv = ws[192 + l], sv = ws[64 + l];
    for (int m = 1; m < 64; m <<= 1){ cv += __shfl_xor(cv, m); sv += __shfl_xor(sv, m); }
    if (l == 0) out[NROWS] = (sv > 0.f) ? cv / fmaxf(sv, 1.f) : 0.f;
}

extern "C" void kernel_launch(void* const* d_in, const int* in_sizes, int n_in,
                              void* d_out, int out_size, void* d_ws, size_t ws_size,
                              hipStream_t stream) {
    const float* xc     = (const float*)d_in[0];
    const float* xs     = (const float*)d_in[1];
    const int*   labels = (const int*)d_in[2];
    const int*   mask   = (const int*)d_in[3];
    const float* ce_w1  = (const float*)d_in[4];
    const float* ce_b1  = (const float*)d_in[5];
    const float* ce_w2  = (const float*)d_in[6];
    const float* ce_b2  = (const float*)d_in[7];
    const float* se_w1  = (const float*)d_in[8];
    const float* se_b1  = (const float*)d_in[9];
    const float* se_w2  = (const float*)d_in[10];
    const float* se_b2  = (const float*)d_in[11];
    const float* cd_g   = (const float*)d_in[12];
    const float* cd_b   = (const float*)d_in[13];
    const float* cd_w1  = (const float*)d_in[14];
    const float* cd_b1  = (const float*)d_in[15];
    const float* cd_w2  = (const float*)d_in[16];
    const float* cd_b2  = (const float*)d_in[17];
    const float* jd_g   = (const float*)d_in[18];
    const float* jd_b   = (const float*)d_in[19];
    const float* jd_w1  = (const float*)d_in[20];
    const float* jd_b1  = (const float*)d_in[21];
    const float* jd_w2  = (const float*)d_in[22];
    const float* jd_b2  = (const float*)d_in[23];
    float* ws  = (float*)d_ws;
    float* out = (float*)d_out;

    k_prep<<<513, 256, 0, stream>>>(ce_w1, ce_w2, se_w1, se_w2, cd_w1, jd_w1,
                                    ce_b1, ce_b2, se_b1, se_b2, cd_g, cd_b,
                                    cd_b1, jd_g, jd_b, jd_b1, cd_w2, jd_w2,
                                    mask, labels, ws);
    k_main<<<4096, 256, 0, stream>>>(xc, xs, labels, mask, cd_b2, jd_b2, ws, out);
    k_aux1<<<64, 256, 0, stream>>>(ws);
    k_aux2<<<1, 64, 0, stream>>>(ws, out);
}